// Round 15
// baseline (225.189 us; speedup 1.0000x reference)
//
#include <hip/hip_runtime.h>
#include <hip/hip_fp16.h>
#include <math.h>
#include <string.h>

#define Dd 192
#define Hh 192
#define Ww 192
#define K  11
#define R  5

#define DC 16             // output planes per wave chunk
#define NP 26             // input planes per chunk = DC + 2R

typedef _Float16 h4  __attribute__((ext_vector_type(4)));
typedef float    f32x4 __attribute__((ext_vector_type(4)));

struct GWF { float gf[K]; unsigned int g2[K]; };  // f32 + half2(g,g) forms

static __device__ __forceinline__ __half2 u2h2(unsigned int u) {
    union { unsigned int u; __half2 h; } x; x.u = u; return x.h;
}
static __device__ __forceinline__ unsigned int h22u(__half2 h) {
    union { __half2 h; unsigned int u; } x; x.h = h; return x.u;
}
static __device__ __forceinline__ unsigned int pk(float a, float b) {
    typedef __fp16 f16x2 __attribute__((ext_vector_type(2)));
    f16x2 r = __builtin_amdgcn_cvt_pkrtz(a, b);
    union { f16x2 v; unsigned int u; } x; x.v = r; return x.u;
}
static __device__ __forceinline__ unsigned int hmul2u(unsigned int a, unsigned int b) {
    return h22u(__hmul2(u2h2(a), u2h2(b)));
}
// banded-weight select: g[j] for j in [0,10], else 0
static __device__ __forceinline__ float wsel(int j, const GWF& G) {
    float v = 0.f;
#pragma unroll
    for (int t = 0; t < K; ++t) v = (j == t) ? G.gf[t] : v;
    return v;
}
// D = A(16x16 f16) * B(16x16 f16) + C, fragments as 2 dwords each
static __device__ __forceinline__ f32x4 MFMA(unsigned int a0, unsigned int a1,
                                             unsigned int b0, unsigned int b1,
                                             f32x4 c) {
    union { unsigned int u[2]; h4 h; } A, B;
    A.u[0] = a0; A.u[1] = a1; B.u[0] = b0; B.u[1] = b1;
    return __builtin_amdgcn_mfma_f32_16x16x16f16(A.h, B.h, c, 0, 0, 0);
}

// Transposed MFMA chaining (lane = image COLUMN -> coalesced loads):
//   conv-H: D1 = S^T x G   (A = data, lane=col, regs=4 consecutive rows)
//   conv-W: D2 = D1^T x G  (D1 fragment feeds A directly; same band G)
// Loads are lane-coalesced dwords (4 x 64B segments per instruction vs ~50
// scattered lines for the old lane=row float4 pattern).
__global__ __launch_bounds__(256, 2) void fused_ssim(
    const float* __restrict__ gr, const float* __restrict__ gt,
    GWF gw, double* __restrict__ acc_g)
{
    __shared__ float wsum[4];

    const int tid  = threadIdx.x;
    const int wv   = tid >> 6;
    const int lane = tid & 63;
    const int n16  = lane & 15;    // image col within chunk / r_out / w_out
    const int g4   = lane >> 4;    // lane group 0..3

    // XCD-chunked swizzle, z-fastest (432 = 8 * 54 exactly)
    const int bid  = blockIdx.x;                  // 0..431
    const int wgid = (bid & 7) * 54 + (bid >> 3);
    const int z4   = wgid % 12;
    const int yx   = wgid / 12;
    const int hy   = yx % 12;
    const int bx   = yx / 12;

    const int w0 = (bx * 4 + wv) * 16;
    const int h0 = hy * 16;
    const int d0 = z4 * DC;

    // ---- load geometry: row = h0-8+16kc+4g4+i (kc,i), col = w0-8+16c16+n16
    int addr[2][2][4]; float amf[2][2][4];
#pragma unroll
    for (int kc = 0; kc < 2; ++kc)
#pragma unroll
    for (int i = 0; i < 4; ++i) {
        const int row  = h0 - 8 + 16 * kc + 4 * g4 + i;
        const bool rok = (row >= 0) && (row < Hh);
        const int rcl  = row < 0 ? 0 : (row >= Hh ? Hh - 1 : row);
#pragma unroll
        for (int c16 = 0; c16 < 2; ++c16) {
            const int col  = w0 - 8 + 16 * c16 + n16;
            const bool cok = (col >= 0) && (col < Ww);
            const int ccl  = col < 0 ? 0 : (col >= Ww ? Ww - 1 : col);
            addr[kc][c16][i] = rcl * Ww + ccl;
            amf[kc][c16][i]  = (rok && cok) ? 0.5f : 0.f;
        }
    }

    // ---- banded weight fragment, shared by BOTH MFMAs: B[k][n] = g[k-n-3]
    unsigned int Bw[2][2];
#pragma unroll
    for (int kc = 0; kc < 2; ++kc) {
        const int kb = 16 * kc + 4 * g4 - n16 - 3;
        Bw[kc][0] = pk(wsel(kb + 0, gw), wsel(kb + 1, gw));
        Bw[kc][1] = pk(wsel(kb + 2, gw), wsel(kb + 3, gw));
    }

    // single-plane register buffer (depth-1 prefetch, no dynamic indexing)
    float pxv[2][2][4], pyv[2][2][4];
    auto LOADP = [&](int p) {
        const int z_ = d0 - R + p;
        const bool zok_ = (z_ >= 0) && (z_ < Dd);
        const int zb_ = (zok_ ? z_ : 0) * Hh * Ww;
#pragma unroll
        for (int kc = 0; kc < 2; ++kc)
#pragma unroll
        for (int c16 = 0; c16 < 2; ++c16)
#pragma unroll
        for (int i = 0; i < 4; ++i) {
            pxv[kc][c16][i] = gr[zb_ + addr[kc][c16][i]];
            pyv[kc][c16][i] = gt[zb_ + addr[kc][c16][i]];
        }
    };

    unsigned int hist[K][5][2];   // conv-D ring: 11 planes x 5 fields x 2 dwords
#pragma unroll
    for (int t = 0; t < K; ++t)
#pragma unroll
        for (int f = 0; f < 5; ++f) { hist[t][f][0] = 0u; hist[t][f][1] = 0u; }

    float ssim_acc = 0.0f;
    LOADP(0);

#pragma unroll
    for (int ip = 0; ip < NP; ++ip) {
        const int j = ip % K;                 // compile-time (full unroll)
        const int z = d0 - R + ip;
        const bool zok = (z >= 0) && (z < Dd);

        // ---- stage 5 field A-fragments (lane=col, regs=4 rows) ----
        unsigned int stgf[2][2][5][2];   // kc, c16, field, dword
#pragma unroll
        for (int kc = 0; kc < 2; ++kc)
#pragma unroll
        for (int c16 = 0; c16 < 2; ++c16) {
            const float A0 = zok ? amf[kc][c16][0] : 0.f;
            const float A1 = zok ? amf[kc][c16][1] : 0.f;
            const float A2_ = zok ? amf[kc][c16][2] : 0.f;
            const float A3 = zok ? amf[kc][c16][3] : 0.f;
            const unsigned int hx0 = pk(fmaf(pxv[kc][c16][0], A0, A0),
                                        fmaf(pxv[kc][c16][1], A1, A1));
            const unsigned int hx1 = pk(fmaf(pxv[kc][c16][2], A2_, A2_),
                                        fmaf(pxv[kc][c16][3], A3, A3));
            const unsigned int hy0 = pk(fmaf(pyv[kc][c16][0], A0, A0),
                                        fmaf(pyv[kc][c16][1], A1, A1));
            const unsigned int hy1 = pk(fmaf(pyv[kc][c16][2], A2_, A2_),
                                        fmaf(pyv[kc][c16][3], A3, A3));
            stgf[kc][c16][0][0] = hx0;             stgf[kc][c16][0][1] = hx1;
            stgf[kc][c16][1][0] = hy0;             stgf[kc][c16][1][1] = hy1;
            stgf[kc][c16][2][0] = hmul2u(hx0,hx0); stgf[kc][c16][2][1] = hmul2u(hx1,hx1);
            stgf[kc][c16][3][0] = hmul2u(hy0,hy0); stgf[kc][c16][3][1] = hmul2u(hy1,hy1);
            stgf[kc][c16][4][0] = hmul2u(hx0,hy0); stgf[kc][c16][4][1] = hmul2u(hx1,hy1);
        }

        if (ip + 1 < NP) LOADP(ip + 1);   // prefetch under the MFMA phase

        // ---- conv-H MFMAs: D1[w][r_out] per col-chunk c16 ----
        unsigned int a2[5][2][2];   // conv-W A operand: field, c16(=w chunk), 2 dwords
#pragma unroll
        for (int c16 = 0; c16 < 2; ++c16)
#pragma unroll
        for (int f = 0; f < 5; ++f) {
            f32x4 dh = {0.f, 0.f, 0.f, 0.f};
            dh = MFMA(stgf[0][c16][f][0], stgf[0][c16][f][1], Bw[0][0], Bw[0][1], dh);
            dh = MFMA(stgf[1][c16][f][0], stgf[1][c16][f][1], Bw[1][0], Bw[1][1], dh);
            a2[f][c16][0] = pk(dh[0], dh[1]);
            a2[f][c16][1] = pk(dh[2], dh[3]);
        }

        // ---- conv-W MFMAs: D2[r][w_out] = D1^T x G (same band) ----
#pragma unroll
        for (int f = 0; f < 5; ++f) {
            f32x4 o = {0.f, 0.f, 0.f, 0.f};
            o = MFMA(a2[f][0][0], a2[f][0][1], Bw[0][0], Bw[0][1], o);
            o = MFMA(a2[f][1][0], a2[f][1][1], Bw[1][0], Bw[1][1], o);
            hist[j][f][0] = pk(o[0], o[1]);   // rows 4g4+0,1 (col n16)
            hist[j][f][1] = pk(o[2], o[3]);   // rows 4g4+2,3
        }

        // ---- conv-D + SSIM (ring full from ip>=10) ----
        if (ip >= 2 * R) {
            __half2 s[5][2];
#pragma unroll
            for (int f = 0; f < 5; ++f) { s[f][0] = u2h2(0u); s[f][1] = u2h2(0u); }
#pragma unroll
            for (int t7 = 0; t7 < K; ++t7) {
                const int sl = (j + 1 + t7) % K;   // compile-time
                const __half2 g = u2h2(gw.g2[t7]);
#pragma unroll
                for (int f = 0; f < 5; ++f) {
                    s[f][0] = __hfma2(g, u2h2(hist[sl][f][0]), s[f][0]);
                    s[f][1] = __hfma2(g, u2h2(hist[sl][f][1]), s[f][1]);
                }
            }
            const float C1 = 1e-4f, C2 = 9e-4f;
#pragma unroll
            for (int p = 0; p < 2; ++p) {
#pragma unroll
                for (int col = 0; col < 2; ++col) {
                    const float m1  = col ? __high2float(s[0][p]) : __low2float(s[0][p]);
                    const float m2  = col ? __high2float(s[1][p]) : __low2float(s[1][p]);
                    const float e11 = col ? __high2float(s[2][p]) : __low2float(s[2][p]);
                    const float e22 = col ? __high2float(s[3][p]) : __low2float(s[3][p]);
                    const float e12 = col ? __high2float(s[4][p]) : __low2float(s[4][p]);
                    const float mu1sq = m1 * m1, mu2sq = m2 * m2, mu12 = m1 * m2;
                    const float s11 = e11 - mu1sq;
                    const float s22 = e22 - mu2sq;
                    const float s12 = e12 - mu12;
                    const float num = (2.f * mu12 + C1) * (2.f * s12 + C2);
                    const float den = (mu1sq + mu2sq + C1) * (s11 + s22 + C2);
                    ssim_acc += num * __builtin_amdgcn_rcpf(den);
                }
            }
        }
    }

    // ---- reduction: wave shuffle, then one cross-wave combine ----
    float v = ssim_acc;
#pragma unroll
    for (int o = 32; o > 0; o >>= 1) v += __shfl_down(v, o);
    if (lane == 0) wsum[wv] = v;
    __syncthreads();
    if (tid == 0) atomicAdd(acc_g, (double)(wsum[0] + wsum[1] + wsum[2] + wsum[3]));
}

__global__ void k4_final(const double* __restrict__ acc, float* __restrict__ out) {
    if (threadIdx.x == 0) {
        const double n = (double)((size_t)Dd * Hh * Ww);
        out[0] = (float)(1.0 - (*acc) / n);
    }
}

// host-side float -> half (RNE)
static unsigned short f2h(float x) {
    unsigned int u; memcpy(&u, &x, 4);
    unsigned int s = (u >> 16) & 0x8000u;
    int e = (int)((u >> 23) & 0xffu) - 112;
    unsigned int m = u & 0x7fffffu;
    if (e <= 0) return (unsigned short)s;
    unsigned int mant = m + 0xFFFu + ((m >> 13) & 1u);
    if (mant & 0x800000u) { mant = 0; e += 1; }
    return (unsigned short)(s | ((unsigned)e << 10) | (mant >> 13));
}

extern "C" void kernel_launch(void* const* d_in, const int* in_sizes, int n_in,
                              void* d_out, int out_size, void* d_ws, size_t ws_size,
                              hipStream_t stream) {
    const float* gr = (const float*)d_in[0];
    const float* gt = (const float*)d_in[1];
    float* out = (float*)d_out;

    // 1D normalized gaussian (exact outer-product factorization of the 3D window)
    GWF gw;
    {
        double e[K], s = 0.0;
        for (int i = 0; i < K; ++i) {
            const double a = (double)((i - R) * (i - R));
            e[i] = exp(-a / (2.0 * 1.5 * 1.5));
            s += e[i];
        }
        for (int i = 0; i < K; ++i) {
            gw.gf[i] = (float)(e[i] / s);
            unsigned short h = f2h(gw.gf[i]);
            gw.g2[i] = (unsigned int)h | ((unsigned int)h << 16);
        }
    }

    double* acc = (double*)d_ws;
    (void)hipMemsetAsync(d_ws, 0, sizeof(double), stream);

    // 4 waves/block; wave tile = 16 cols x 16 rows x 16 planes
    // grid: 3(bx) x 12(hy) x 12(z) = 432 blocks
    fused_ssim<<<432, 256, 0, stream>>>(gr, gt, gw, acc);

    k4_final<<<1, 64, 0, stream>>>(acc, out);
}

// Round 16
// 74.392 us; speedup vs baseline: 3.0271x; 3.0271x over previous
//
#include <hip/hip_runtime.h>
#include <hip/hip_fp16.h>
#include <math.h>
#include <string.h>

#define Dd 192
#define Hh 192
#define Ww 192
#define K  11
#define R  5

#define DC 16             // output planes per wave chunk
#define NP 26             // input planes per chunk = DC + 2R

typedef _Float16 h4  __attribute__((ext_vector_type(4)));
typedef float    f32x4 __attribute__((ext_vector_type(4)));

struct GWF { float gf[K]; unsigned int g2[K]; };  // f32 + half2(g,g) forms

static __device__ __forceinline__ __half2 u2h2(unsigned int u) {
    union { unsigned int u; __half2 h; } x; x.u = u; return x.h;
}
static __device__ __forceinline__ unsigned int h22u(__half2 h) {
    union { __half2 h; unsigned int u; } x; x.h = h; return x.u;
}
static __device__ __forceinline__ unsigned int pk(float a, float b) {
    typedef __fp16 f16x2 __attribute__((ext_vector_type(2)));
    f16x2 r = __builtin_amdgcn_cvt_pkrtz(a, b);
    union { f16x2 v; unsigned int u; } x; x.v = r; return x.u;
}
static __device__ __forceinline__ unsigned int hmul2u(unsigned int a, unsigned int b) {
    return h22u(__hmul2(u2h2(a), u2h2(b)));
}
// banded-weight select: g[j] for j in [0,10], else 0
static __device__ __forceinline__ float wsel(int j, const GWF& G) {
    float v = 0.f;
#pragma unroll
    for (int t = 0; t < K; ++t) v = (j == t) ? G.gf[t] : v;
    return v;
}
// D = A(16x16 f16) * B(16x16 f16) + C, fragments as 2 dwords each
static __device__ __forceinline__ f32x4 MFMA(unsigned int a0, unsigned int a1,
                                             unsigned int b0, unsigned int b1,
                                             f32x4 c) {
    union { unsigned int u[2]; h4 h; } A, B;
    A.u[0] = a0; A.u[1] = a1; B.u[0] = b0; B.u[1] = b1;
    return __builtin_amdgcn_mfma_f32_16x16x16f16(A.h, B.h, c, 0, 0, 0);
}

// r11 structure (verified, 64us) with finer grid granularity:
// 2 waves/block -> 864 blocks = 3.375 blocks/CU (was 432 = 1.69, 2:1 CU
// imbalance). Independent barrier-free waves; setprio(1) on MFMA cluster.
__global__ __launch_bounds__(128, 2) void fused_ssim(
    const float* __restrict__ gr, const float* __restrict__ gt,
    GWF gw, double* __restrict__ acc_g)
{
    __shared__ float wsum[2];

    const int tid  = threadIdx.x;
    const int wv   = tid >> 6;
    const int lane = tid & 63;
    const int n16  = lane & 15;    // MFMA 16-index (row of A / col of B,D)
    const int g4   = lane >> 4;    // lane group 0..3

    // XCD-chunked swizzle, z-fastest (864 = 8 * 108 exactly)
    const int bid  = blockIdx.x;                  // 0..863
    const int wgid = (bid & 7) * 108 + (bid >> 3);
    const int z4   = wgid % 12;
    const int yx   = wgid / 12;
    const int hy   = yx % 12;
    const int bx   = yx / 12;                     // 0..5

    const int w0 = (bx * 2 + wv) * 16;
    const int h0 = hy * 16;
    const int d0 = z4 * DC;

    // ---- load geometry: (rc,kc): row = h0-5+16rc+n16, col = w0-8+16kc+4*g4
    int addr[2][2]; float amf[2][2];
#pragma unroll
    for (int rc = 0; rc < 2; ++rc)
#pragma unroll
    for (int kc = 0; kc < 2; ++kc) {
        const int gh   = h0 - R + 16 * rc + n16;
        const bool rok = (gh >= 0) && (gh < Hh);
        const int ghc  = gh < 0 ? 0 : (gh >= Hh ? Hh - 1 : gh);
        const int gx   = w0 - 8 + 16 * kc + 4 * g4;
        const bool cok = (gx >= 0) && (gx + 3 < Ww);
        const int gxc  = gx < 0 ? 0 : (gx > Ww - 4 ? Ww - 4 : gx);
        addr[rc][kc] = ghc * Ww + gxc;
        amf[rc][kc]  = (rok && cok) ? 0.5f : 0.f;
    }

    // ---- banded weight fragments (computed once per wave) ----
    unsigned int Bw[2][2];   // conv-W B-frag: B[k][n]=g[k-n-3]
#pragma unroll
    for (int kc = 0; kc < 2; ++kc) {
        const int kb = 16 * kc + 4 * g4 - n16 - 3;
        Bw[kc][0] = pk(wsel(kb + 0, gw), wsel(kb + 1, gw));
        Bw[kc][1] = pk(wsel(kb + 2, gw), wsel(kb + 3, gw));
    }
    unsigned int Ah[2][2];   // conv-H A-frag: A[m][k]=g[k-m]
#pragma unroll
    for (int kc = 0; kc < 2; ++kc) {
        const int kb = 16 * kc + 4 * g4 - n16;
        Ah[kc][0] = pk(wsel(kb + 0, gw), wsel(kb + 1, gw));
        Ah[kc][1] = pk(wsel(kb + 2, gw), wsel(kb + 3, gw));
    }

    float4 px[2][2], py[2][2];
    auto LOADP = [&](int p) {
        const int z  = d0 - R + p;
        const bool zok = (z >= 0) && (z < Dd);
        const int zb = (zok ? z : 0) * Hh * Ww;
#pragma unroll
        for (int rc = 0; rc < 2; ++rc)
#pragma unroll
        for (int kc = 0; kc < 2; ++kc) {
            px[rc][kc] = *(const float4*)(gr + zb + addr[rc][kc]);
            py[rc][kc] = *(const float4*)(gt + zb + addr[rc][kc]);
        }
    };

    unsigned int hist[K][5][2];   // conv-D ring: 11 planes x 5 fields x 2 dwords
#pragma unroll
    for (int t = 0; t < K; ++t)
#pragma unroll
        for (int f = 0; f < 5; ++f) { hist[t][f][0] = 0u; hist[t][f][1] = 0u; }

    float ssim_acc = 0.0f;
    LOADP(0);

#pragma unroll
    for (int ip = 0; ip < NP; ++ip) {
        const int j = ip % K;                 // compile-time (full unroll)
        const int z = d0 - R + ip;
        const bool zok = (z >= 0) && (z < Dd);

        // ---- stage all fields (consumes px/py) ----
        unsigned int stgf[2][5][2][2];   // rc, field, kc, dword
#pragma unroll
        for (int rc = 0; rc < 2; ++rc)
#pragma unroll
        for (int kc = 0; kc < 2; ++kc) {
            const float A = zok ? amf[rc][kc] : 0.f;
            const float4 X = px[rc][kc], Y = py[rc][kc];
            const unsigned int hx0 = pk(fmaf(X.x, A, A), fmaf(X.y, A, A));
            const unsigned int hx1 = pk(fmaf(X.z, A, A), fmaf(X.w, A, A));
            const unsigned int hy0 = pk(fmaf(Y.x, A, A), fmaf(Y.y, A, A));
            const unsigned int hy1 = pk(fmaf(Y.z, A, A), fmaf(Y.w, A, A));
            stgf[rc][0][kc][0] = hx0;             stgf[rc][0][kc][1] = hx1;
            stgf[rc][1][kc][0] = hy0;             stgf[rc][1][kc][1] = hy1;
            stgf[rc][2][kc][0] = hmul2u(hx0,hx0); stgf[rc][2][kc][1] = hmul2u(hx1,hx1);
            stgf[rc][3][kc][0] = hmul2u(hy0,hy0); stgf[rc][3][kc][1] = hmul2u(hy1,hy1);
            stgf[rc][4][kc][0] = hmul2u(hx0,hy0); stgf[rc][4][kc][1] = hmul2u(hx1,hy1);
        }

        if (ip + 1 < NP) LOADP(ip + 1);   // prefetch under the MFMA phase

        __builtin_amdgcn_s_setprio(1);

        // ---- conv-W MFMAs ----
        unsigned int b2[5][2][2];   // conv-H B operand: field, rc, 2 dwords
#pragma unroll
        for (int rc = 0; rc < 2; ++rc)
#pragma unroll
        for (int f = 0; f < 5; ++f) {
            f32x4 cw = {0.f, 0.f, 0.f, 0.f};
            cw = MFMA(stgf[rc][f][0][0], stgf[rc][f][0][1], Bw[0][0], Bw[0][1], cw);
            cw = MFMA(stgf[rc][f][1][0], stgf[rc][f][1][1], Bw[1][0], Bw[1][1], cw);
            b2[f][rc][0] = pk(cw[0], cw[1]);
            b2[f][rc][1] = pk(cw[2], cw[3]);
        }

        // ---- conv-H MFMAs (b2 is already in B-layout) ----
#pragma unroll
        for (int f = 0; f < 5; ++f) {
            f32x4 ch = {0.f, 0.f, 0.f, 0.f};
            ch = MFMA(Ah[0][0], Ah[0][1], b2[f][0][0], b2[f][0][1], ch);
            ch = MFMA(Ah[1][0], Ah[1][1], b2[f][1][0], b2[f][1][1], ch);
            hist[j][f][0] = pk(ch[0], ch[1]);   // rows 4g4+0,1 (col n16)
            hist[j][f][1] = pk(ch[2], ch[3]);   // rows 4g4+2,3
        }

        __builtin_amdgcn_s_setprio(0);

        // ---- conv-D + SSIM (ring full from ip>=10) ----
        if (ip >= 2 * R) {
            __half2 s[5][2];
#pragma unroll
            for (int f = 0; f < 5; ++f) { s[f][0] = u2h2(0u); s[f][1] = u2h2(0u); }
#pragma unroll
            for (int t7 = 0; t7 < K; ++t7) {
                const int sl = (j + 1 + t7) % K;   // compile-time
                const __half2 g = u2h2(gw.g2[t7]);
#pragma unroll
                for (int f = 0; f < 5; ++f) {
                    s[f][0] = __hfma2(g, u2h2(hist[sl][f][0]), s[f][0]);
                    s[f][1] = __hfma2(g, u2h2(hist[sl][f][1]), s[f][1]);
                }
            }
            const float C1 = 1e-4f, C2 = 9e-4f;
#pragma unroll
            for (int p = 0; p < 2; ++p) {
#pragma unroll
                for (int col = 0; col < 2; ++col) {
                    const float m1  = col ? __high2float(s[0][p]) : __low2float(s[0][p]);
                    const float m2  = col ? __high2float(s[1][p]) : __low2float(s[1][p]);
                    const float e11 = col ? __high2float(s[2][p]) : __low2float(s[2][p]);
                    const float e22 = col ? __high2float(s[3][p]) : __low2float(s[3][p]);
                    const float e12 = col ? __high2float(s[4][p]) : __low2float(s[4][p]);
                    const float mu1sq = m1 * m1, mu2sq = m2 * m2, mu12 = m1 * m2;
                    const float s11 = e11 - mu1sq;
                    const float s22 = e22 - mu2sq;
                    const float s12 = e12 - mu12;
                    const float num = (2.f * mu12 + C1) * (2.f * s12 + C2);
                    const float den = (mu1sq + mu2sq + C1) * (s11 + s22 + C2);
                    ssim_acc += num * __builtin_amdgcn_rcpf(den);
                }
            }
        }
    }

    // ---- reduction: wave shuffle, then one cross-wave combine ----
    float v = ssim_acc;
#pragma unroll
    for (int o = 32; o > 0; o >>= 1) v += __shfl_down(v, o);
    if (lane == 0) wsum[wv] = v;
    __syncthreads();
    if (tid == 0) atomicAdd(acc_g, (double)(wsum[0] + wsum[1]));
}

__global__ void k4_final(const double* __restrict__ acc, float* __restrict__ out) {
    if (threadIdx.x == 0) {
        const double n = (double)((size_t)Dd * Hh * Ww);
        out[0] = (float)(1.0 - (*acc) / n);
    }
}

// host-side float -> half (RNE)
static unsigned short f2h(float x) {
    unsigned int u; memcpy(&u, &x, 4);
    unsigned int s = (u >> 16) & 0x8000u;
    int e = (int)((u >> 23) & 0xffu) - 112;
    unsigned int m = u & 0x7fffffu;
    if (e <= 0) return (unsigned short)s;
    unsigned int mant = m + 0xFFFu + ((m >> 13) & 1u);
    if (mant & 0x800000u) { mant = 0; e += 1; }
    return (unsigned short)(s | ((unsigned)e << 10) | (mant >> 13));
}

extern "C" void kernel_launch(void* const* d_in, const int* in_sizes, int n_in,
                              void* d_out, int out_size, void* d_ws, size_t ws_size,
                              hipStream_t stream) {
    const float* gr = (const float*)d_in[0];
    const float* gt = (const float*)d_in[1];
    float* out = (float*)d_out;

    // 1D normalized gaussian (exact outer-product factorization of the 3D window)
    GWF gw;
    {
        double e[K], s = 0.0;
        for (int i = 0; i < K; ++i) {
            const double a = (double)((i - R) * (i - R));
            e[i] = exp(-a / (2.0 * 1.5 * 1.5));
            s += e[i];
        }
        for (int i = 0; i < K; ++i) {
            gw.gf[i] = (float)(e[i] / s);
            unsigned short h = f2h(gw.gf[i]);
            gw.g2[i] = (unsigned int)h | ((unsigned int)h << 16);
        }
    }

    double* acc = (double*)d_ws;
    (void)hipMemsetAsync(d_ws, 0, sizeof(double), stream);

    // 2 waves/block; wave tile = 16 cols x 16 rows x 16 planes
    // grid: 6(bx*2) x 12(hy) x 12(z) = 864 blocks = 3.375 blocks/CU
    fused_ssim<<<864, 128, 0, stream>>>(gr, gt, gw, acc);

    k4_final<<<1, 64, 0, stream>>>(acc, out);
}

// Round 17
// 64.844 us; speedup vs baseline: 3.4728x; 1.1472x over previous
//
#include <hip/hip_runtime.h>
#include <hip/hip_fp16.h>
#include <math.h>
#include <string.h>

#define Dd 192
#define Hh 192
#define Ww 192
#define K  11
#define R  5

#define DC 16             // output planes per wave-tile chunk
#define NP 26             // input planes per chunk (DC + 2R)

typedef _Float16 h4  __attribute__((ext_vector_type(4)));
typedef float    f32x4 __attribute__((ext_vector_type(4)));

struct GWF { float gf[K]; unsigned int g2[K]; };  // f32 + half2(g,g) forms

static __device__ __forceinline__ __half2 u2h2(unsigned int u) {
    union { unsigned int u; __half2 h; } x; x.u = u; return x.h;
}
static __device__ __forceinline__ unsigned int h22u(__half2 h) {
    union { __half2 h; unsigned int u; } x; x.h = h; return x.u;
}
static __device__ __forceinline__ unsigned int pk(float a, float b) {
    typedef __fp16 f16x2 __attribute__((ext_vector_type(2)));
    f16x2 r = __builtin_amdgcn_cvt_pkrtz(a, b);
    union { f16x2 v; unsigned int u; } x; x.v = r; return x.u;
}
// banded-weight select: g[j] for j in [0,10], else 0
static __device__ __forceinline__ float wsel(int j, const GWF& G) {
    float v = 0.f;
#pragma unroll
    for (int t = 0; t < K; ++t) v = (j == t) ? G.gf[t] : v;
    return v;
}
// D = A(16x16 f16) * B(16x16 f16) + C, fragments as 2 dwords each
static __device__ __forceinline__ f32x4 MFMA(unsigned int a0, unsigned int a1,
                                             unsigned int b0, unsigned int b1,
                                             f32x4 c) {
    union { unsigned int u[2]; h4 h; } A, B;
    A.u[0] = a0; A.u[1] = a1; B.u[0] = b0; B.u[1] = b1;
    return __builtin_amdgcn_mfma_f32_16x16x16f16(A.h, B.h, c, 0, 0, 0);
}

// r11 structure (64us champion) + s_setprio(1) around the MFMA cluster.
// Fully register-resident fused SSIM: global->regs (MFMA A-layout),
// conv-W = banded MFMA, conv-H = banded MFMA chained off conv-W's D,
// conv-D = fp16 register ring, SSIM + wave reduce. No LDS in the hot loop.
__global__ __launch_bounds__(256, 2) void fused_ssim(
    const float* __restrict__ gr, const float* __restrict__ gt,
    GWF gw, double* __restrict__ acc_g)
{
    __shared__ float wsum[4];

    const int tid  = threadIdx.x;
    const int wv   = tid >> 6;
    const int lane = tid & 63;
    const int n16  = lane & 15;    // MFMA 16-index (row of A / col of B,D)
    const int g4   = lane >> 4;    // lane group 0..3

    // XCD-chunked swizzle, z-fastest (D-halo neighbors share an XCD's L2)
    const int bid  = blockIdx.x;                 // 0..431
    const int wgid = (bid & 7) * 54 + (bid >> 3);
    const int z4   = wgid % 12;
    const int yx   = wgid / 12;
    const int hy   = yx % 12;
    const int bx   = yx / 12;

    const int w0 = (bx * 4 + wv) * 16;
    const int h0 = hy * 16;
    const int d0 = z4 * DC;

    // ---- load geometry: (rc,kc): row = h0-5+16rc+n16, col = w0-8+16kc+4*g4
    int addr[2][2]; float amf[2][2];
#pragma unroll
    for (int rc = 0; rc < 2; ++rc)
#pragma unroll
    for (int kc = 0; kc < 2; ++kc) {
        const int gh   = h0 - R + 16 * rc + n16;
        const bool rok = (gh >= 0) && (gh < Hh);
        const int ghc  = gh < 0 ? 0 : (gh >= Hh ? Hh - 1 : gh);
        const int gx   = w0 - 8 + 16 * kc + 4 * g4;
        const bool cok = (gx >= 0) && (gx + 3 < Ww);
        const int gxc  = gx < 0 ? 0 : (gx > Ww - 4 ? Ww - 4 : gx);
        addr[rc][kc] = ghc * Ww + gxc;
        amf[rc][kc]  = (rok && cok) ? 0.5f : 0.f;
    }

    // ---- banded weight fragments (computed once) ----
    // conv-W B-frag: B[k][n]=g[k-n-3], n=n16 (out col), k=16kc+4g4+i
    unsigned int Bw[2][2];
#pragma unroll
    for (int kc = 0; kc < 2; ++kc) {
        const int kb = 16 * kc + 4 * g4 - n16 - 3;
        Bw[kc][0] = pk(wsel(kb + 0, gw), wsel(kb + 1, gw));
        Bw[kc][1] = pk(wsel(kb + 2, gw), wsel(kb + 3, gw));
    }
    // conv-H A-frag: A[m][k]=g[k-m], m=n16 (out row), k=16kc+4g4+i
    unsigned int Ah[2][2];
#pragma unroll
    for (int kc = 0; kc < 2; ++kc) {
        const int kb = 16 * kc + 4 * g4 - n16;
        Ah[kc][0] = pk(wsel(kb + 0, gw), wsel(kb + 1, gw));
        Ah[kc][1] = pk(wsel(kb + 2, gw), wsel(kb + 3, gw));
    }

    float4 px[2][2], py[2][2];
    auto LOADP = [&](int p) {
        const int z  = d0 - R + p;
        const bool zok = (z >= 0) && (z < Dd);
        const int zb = (zok ? z : 0) * Hh * Ww;
#pragma unroll
        for (int rc = 0; rc < 2; ++rc)
#pragma unroll
        for (int kc = 0; kc < 2; ++kc) {
            px[rc][kc] = *(const float4*)(gr + zb + addr[rc][kc]);
            py[rc][kc] = *(const float4*)(gt + zb + addr[rc][kc]);
        }
    };

    unsigned int hist[K][5][2];   // conv-D ring: 11 planes x 5 fields x 2 dwords
#pragma unroll
    for (int t = 0; t < K; ++t)
#pragma unroll
        for (int f = 0; f < 5; ++f) { hist[t][f][0] = 0u; hist[t][f][1] = 0u; }

    float ssim_acc = 0.0f;
    LOADP(0);

    for (int c = 0; c < 3; ++c) {
#pragma unroll
        for (int j = 0; j < K; ++j) {
            const int ip = c * K + j;
            if (ip < NP) {
                const int z = d0 - R + ip;
                const bool zok = (z >= 0) && (z < Dd);

                // ---- stage fields (f16 A-frags) + conv-W MFMAs, per row-chunk
                unsigned int b2[5][2][2];   // conv-H B operand: field, rc, 2 dwords
#pragma unroll
                for (int rc = 0; rc < 2; ++rc) {
                    unsigned int stgf[5][2][2];   // field, kc, dword (transient)
#pragma unroll
                    for (int kc = 0; kc < 2; ++kc) {
                        const float A = zok ? amf[rc][kc] : 0.f;
                        const float4 X = px[rc][kc], Y = py[rc][kc];
                        const float xs0 = fmaf(X.x, A, A), xs1 = fmaf(X.y, A, A);
                        const float xs2 = fmaf(X.z, A, A), xs3 = fmaf(X.w, A, A);
                        const float ys0 = fmaf(Y.x, A, A), ys1 = fmaf(Y.y, A, A);
                        const float ys2 = fmaf(Y.z, A, A), ys3 = fmaf(Y.w, A, A);
                        stgf[0][kc][0] = pk(xs0, xs1);          stgf[0][kc][1] = pk(xs2, xs3);
                        stgf[1][kc][0] = pk(ys0, ys1);          stgf[1][kc][1] = pk(ys2, ys3);
                        stgf[2][kc][0] = pk(xs0*xs0, xs1*xs1);  stgf[2][kc][1] = pk(xs2*xs2, xs3*xs3);
                        stgf[3][kc][0] = pk(ys0*ys0, ys1*ys1);  stgf[3][kc][1] = pk(ys2*ys2, ys3*ys3);
                        stgf[4][kc][0] = pk(xs0*ys0, xs1*ys1);  stgf[4][kc][1] = pk(xs2*ys2, xs3*ys3);
                    }
                    __builtin_amdgcn_s_setprio(1);
#pragma unroll
                    for (int f = 0; f < 5; ++f) {
                        f32x4 cw = {0.f, 0.f, 0.f, 0.f};
                        cw = MFMA(stgf[f][0][0], stgf[f][0][1], Bw[0][0], Bw[0][1], cw);
                        cw = MFMA(stgf[f][1][0], stgf[f][1][1], Bw[1][0], Bw[1][1], cw);
                        b2[f][rc][0] = pk(cw[0], cw[1]);
                        b2[f][rc][1] = pk(cw[2], cw[3]);
                    }
                    __builtin_amdgcn_s_setprio(0);
                }

                if (ip + 1 < NP) LOADP(ip + 1);   // prefetch next plane

                // ---- conv-H MFMAs (chained: b2 is already in B-layout) ----
                __builtin_amdgcn_s_setprio(1);
#pragma unroll
                for (int f = 0; f < 5; ++f) {
                    f32x4 ch = {0.f, 0.f, 0.f, 0.f};
                    ch = MFMA(Ah[0][0], Ah[0][1], b2[f][0][0], b2[f][0][1], ch);
                    ch = MFMA(Ah[1][0], Ah[1][1], b2[f][1][0], b2[f][1][1], ch);
                    hist[j][f][0] = pk(ch[0], ch[1]);   // rows 4g4+0,1 (col n16)
                    hist[j][f][1] = pk(ch[2], ch[3]);   // rows 4g4+2,3
                }
                __builtin_amdgcn_s_setprio(0);

                // ---- conv-D + SSIM (ring full from ip>=10) ----
                if (ip >= 2 * R) {
                    __half2 s[5][2];
#pragma unroll
                    for (int f = 0; f < 5; ++f) { s[f][0] = u2h2(0u); s[f][1] = u2h2(0u); }
#pragma unroll
                    for (int t7 = 0; t7 < K; ++t7) {
                        const int sl = (j + 1 + t7) % K;   // static after unroll
                        const __half2 g = u2h2(gw.g2[t7]);
#pragma unroll
                        for (int f = 0; f < 5; ++f) {
                            s[f][0] = __hfma2(g, u2h2(hist[sl][f][0]), s[f][0]);
                            s[f][1] = __hfma2(g, u2h2(hist[sl][f][1]), s[f][1]);
                        }
                    }
                    const float C1 = 1e-4f, C2 = 9e-4f;
#pragma unroll
                    for (int p = 0; p < 2; ++p) {
#pragma unroll
                        for (int col = 0; col < 2; ++col) {
                            const float m1  = col ? __high2float(s[0][p]) : __low2float(s[0][p]);
                            const float m2  = col ? __high2float(s[1][p]) : __low2float(s[1][p]);
                            const float e11 = col ? __high2float(s[2][p]) : __low2float(s[2][p]);
                            const float e22 = col ? __high2float(s[3][p]) : __low2float(s[3][p]);
                            const float e12 = col ? __high2float(s[4][p]) : __low2float(s[4][p]);
                            const float mu1sq = m1 * m1, mu2sq = m2 * m2, mu12 = m1 * m2;
                            const float s11 = e11 - mu1sq;
                            const float s22 = e22 - mu2sq;
                            const float s12 = e12 - mu12;
                            const float num = (2.f * mu12 + C1) * (2.f * s12 + C2);
                            const float den = (mu1sq + mu2sq + C1) * (s11 + s22 + C2);
                            ssim_acc += num * __builtin_amdgcn_rcpf(den);
                        }
                    }
                }
            }
        }
    }

    // ---- reduction: wave shuffle, then one cross-wave combine ----
    float v = ssim_acc;
#pragma unroll
    for (int o = 32; o > 0; o >>= 1) v += __shfl_down(v, o);
    if (lane == 0) wsum[wv] = v;
    __syncthreads();
    if (tid == 0) atomicAdd(acc_g, (double)(wsum[0] + wsum[1] + wsum[2] + wsum[3]));
}

__global__ void k4_final(const double* __restrict__ acc, float* __restrict__ out) {
    if (threadIdx.x == 0) {
        const double n = (double)((size_t)Dd * Hh * Ww);
        out[0] = (float)(1.0 - (*acc) / n);
    }
}

// host-side float -> half (RNE)
static unsigned short f2h(float x) {
    unsigned int u; memcpy(&u, &x, 4);
    unsigned int s = (u >> 16) & 0x8000u;
    int e = (int)((u >> 23) & 0xffu) - 112;
    unsigned int m = u & 0x7fffffu;
    if (e <= 0) return (unsigned short)s;
    unsigned int mant = m + 0xFFFu + ((m >> 13) & 1u);
    if (mant & 0x800000u) { mant = 0; e += 1; }
    return (unsigned short)(s | ((unsigned)e << 10) | (mant >> 13));
}

extern "C" void kernel_launch(void* const* d_in, const int* in_sizes, int n_in,
                              void* d_out, int out_size, void* d_ws, size_t ws_size,
                              hipStream_t stream) {
    const float* gr = (const float*)d_in[0];
    const float* gt = (const float*)d_in[1];
    float* out = (float*)d_out;

    // 1D normalized gaussian (exact outer-product factorization of the 3D window)
    GWF gw;
    {
        double e[K], s = 0.0;
        for (int i = 0; i < K; ++i) {
            const double a = (double)((i - R) * (i - R));
            e[i] = exp(-a / (2.0 * 1.5 * 1.5));
            s += e[i];
        }
        for (int i = 0; i < K; ++i) {
            gw.gf[i] = (float)(e[i] / s);
            unsigned short h = f2h(gw.gf[i]);
            gw.g2[i] = (unsigned int)h | ((unsigned int)h << 16);
        }
    }

    double* acc = (double*)d_ws;
    (void)hipMemsetAsync(d_ws, 0, sizeof(double), stream);

    // 4 waves/block; wave tile = 16 cols x 16 rows x 16 planes
    // grid: 3(bx) x 12(hy) x 12(z) = 432 blocks, 1D with XCD swizzle in-kernel
    fused_ssim<<<432, 256, 0, stream>>>(gr, gt, gw, acc);

    k4_final<<<1, 64, 0, stream>>>(acc, out);
}